// Round 17
// baseline (98.510 us; speedup 1.0000x reference)
//
#include <hip/hip_runtime.h>
#include <hip/hip_bf16.h>

#define B_    32
#define N_    10000
#define G_    256
#define HID_  256
#define EPS_  1e-5f

typedef __attribute__((ext_vector_type(8))) short short8_t;
typedef __attribute__((ext_vector_type(4))) float f32x4;

// prep_k grid segmentation
#define TB_W1  2504            // W1 transpose->bf16: 313 x 8 tiles
#define TB_X   313             // x transpose->bf16: 32 x 10000
#define NB_W2C 64              // W2 -> bf16 cast (no transpose)
#define NB_CMP 256             // mask compaction, one block per g
#define PREP_GRID (TB_W1 + TB_X + NB_W2C + NB_CMP + 1)   // 3138 (+1 zero-row)

#define DKB_  40               // dense-group split-K producer blocks
#define DCH_  250              // genes per dense chunk (40*250 = 10000)
#define MEGA_GRID (DKB_ + 255 + 1)   // 296

#define NTMAX 10               // max 32-gene tiles per sparse group (cap 320)
#define BPKT_ 8192             // u16 per B tile (32 genes x 256 h)
#define APKT_ 1024             // u16 per A tile (32 genes x 32 b)

#define LAP_  264              // LA / lhf pitch in elements (16B-aligned rows)

// ---------------------------------------------------------------------------
// Tiled transpose helper (f32 -> bf16).
// ---------------------------------------------------------------------------
__device__ inline void transpose_tile_bf16(const float* __restrict__ src,
                                           __hip_bfloat16* __restrict__ dst,
                                           int R, int C, int bx, int by, int t,
                                           float (*tile)[33]) {
    int tx = t & 31, ty = t >> 5;      // 32 x 8
    int c0 = bx * 32, r0 = by * 32;
#pragma unroll
    for (int j = 0; j < 4; ++j) {
        int r = r0 + ty + j * 8, c = c0 + tx;
        if (r < R && c < C) tile[ty + j * 8][tx] = src[(size_t)r * C + c];
    }
    __syncthreads();
#pragma unroll
    for (int j = 0; j < 4; ++j) {
        int c = c0 + ty + j * 8, r = r0 + tx;
        if (r < R && c < C)
            dst[(size_t)c * R + r] = __float2bfloat16(tile[tx][ty + j * 8]);
    }
}

// ---------------------------------------------------------------------------
// Fused prep: W1/x -> bf16 transposes, W2 -> bf16 cast, compaction, zero-row.
// ---------------------------------------------------------------------------
__global__ __launch_bounds__(256) void prep_k(const float* __restrict__ W1,
                                              const float* __restrict__ x,
                                              const float* __restrict__ W2,
                                              const float* __restrict__ mask,
                                              __hip_bfloat16* __restrict__ w1bf,
                                              __hip_bfloat16* __restrict__ xtbf,
                                              __hip_bfloat16* __restrict__ w2bf,
                                              int* __restrict__ cnt,
                                              unsigned short* __restrict__ idx,
                                              int* __restrict__ ctr) {
    __shared__ float tile[32][33];
    __shared__ int c;
    int bid = blockIdx.x, t = threadIdx.x;

    if (bid == 0 && t == 0) *ctr = 0;  // reset mega_k producer counter

    if (bid < TB_W1) {
        transpose_tile_bf16(W1, w1bf, HID_, N_, bid % 313, bid / 313, t, tile);
    } else if (bid < TB_W1 + TB_X) {
        transpose_tile_bf16(x, xtbf, B_, N_, bid - TB_W1, 0, t, tile);
    } else if (bid < TB_W1 + TB_X + NB_W2C) {
        int b = bid - (TB_W1 + TB_X);
#pragma unroll
        for (int j = 0; j < 4; ++j) {
            int i = b * 1024 + j * 256 + t;
            w2bf[i] = __float2bfloat16(W2[i]);
        }
    } else if (bid < TB_W1 + TB_X + NB_W2C + NB_CMP) {
        int g = bid - (TB_W1 + TB_X + NB_W2C);
        if (g == 255) return;              // dense group: contiguous, no list
        if (t == 0) c = 0;
        __syncthreads();
        for (int n = t; n < N_; n += 256) {
            if (mask[(size_t)g * N_ + n] != 0.0f) {
                int p = atomicAdd(&c, 1);          // LDS atomic only
                idx[(size_t)g * N_ + p] = (unsigned short)n;
            }
        }
        __syncthreads();
        if (t == 0) cnt[g] = c;
    } else {
        // zero row N_ of w1bf and xtbf (pad-gene target: contributes 0)
        w1bf[(size_t)N_ * 256 + t] = __float2bfloat16(0.f);
        if (t < 32) xtbf[(size_t)N_ * 32 + t] = __float2bfloat16(0.f);
    }
}

// ---------------------------------------------------------------------------
// pack_k: one block per sparse group. Assembles per-32-gene-tile A/B MFMA
// fragments in LDS and streams them out linearly, so mega's phase A is pure
// contiguous b128 loads.
//   B layout (per tile, 8192 u16): [(h>>4)*4 + kg]*128 + (h&15)*8 + j
//   A layout (per tile, 1024 u16): [(b>>4)*4 + kg]*128 + (b&15)*8 + j
//   where within-tile gene kk = kg*8 + j.
// ---------------------------------------------------------------------------
__global__ __launch_bounds__(256) void pack_k(const int* __restrict__ cnt,
                                              const unsigned short* __restrict__ idx,
                                              const uint4* __restrict__ w1bf4,
                                              const unsigned short* __restrict__ xtbf,
                                              unsigned short* __restrict__ bpk,
                                              unsigned short* __restrict__ apk) {
    __shared__ unsigned short LB[BPKT_];   // 16 KB
    __shared__ unsigned short LAx[APKT_];  // 2 KB
    __shared__ int nsl[32];
    const int g = blockIdx.x, t = threadIdx.x;
    const int c = cnt[g];
    const int ntiles = min((c + 31) >> 5, NTMAX);

    unsigned short* obp = bpk + (size_t)g * (NTMAX * BPKT_);
    unsigned short* oap = apk + (size_t)g * (NTMAX * APKT_);

    for (int T = 0; T < ntiles; ++T) {
        __syncthreads();                       // LB/LAx stream-out done
        if (t < 32) {
            int k = T * 32 + t;
            nsl[t] = (k < c) ? (int)idx[(size_t)g * N_ + k] : N_;  // pad->0row
        }
        __syncthreads();

        // ---- B assemble: 32 genes x 32 8-u16 chunks ----
#pragma unroll
        for (int it = 0; it < 4; ++it) {
            int i = it * 256 + t;              // 0..1023
            int kk = i >> 5, ch = i & 31;
            int kg = kk >> 3, j = kk & 7;
            uint4 v = w1bf4[(size_t)nsl[kk] * 32 + ch];   // 512B/row coalesced
            unsigned int uu[4] = {v.x, v.y, v.z, v.w};
#pragma unroll
            for (int e = 0; e < 8; ++e) {
                unsigned short val = (unsigned short)(uu[e >> 1] >> ((e & 1) * 16));
                LB[((ch >> 1) * 4 + kg) * 128 + ((ch & 1) * 8 + e) * 8 + j] = val;
            }
        }
        // ---- A assemble: 32 genes x 32 batches ----
#pragma unroll
        for (int it = 0; it < 4; ++it) {
            int i = it * 256 + t;              // 0..1023
            int kk = i >> 5, b = i & 31;
            int kg = kk >> 3, j = kk & 7;
            LAx[((b >> 4) * 4 + kg) * 128 + (b & 15) * 8 + j] =
                xtbf[(size_t)nsl[kk] * 32 + b];
        }
        __syncthreads();

        // ---- stream out (coalesced uint4) ----
        uint4* ob = (uint4*)(obp + (size_t)T * BPKT_);
#pragma unroll
        for (int it = 0; it < 4; ++it)
            ob[it * 256 + t] = ((const uint4*)LB)[it * 256 + t];
        if (t < 128)
            ((uint4*)(oap + (size_t)T * APKT_))[t] = ((const uint4*)LAx)[t];
    }
}

// ---------------------------------------------------------------------------
// MEGA kernel: MFMA GEMM1 from packed fragments (sparse) / direct gather
// (dense producers), then fused BN1 -> GEMM2 -> BN2.
//   bid <  40  : dense producer (group 255, 250 genes) -> hpartD (f32), ctr++
//   bid 40..294: sparse group g = bid-40: phase A = 4 linear b128 + 4 MFMA
//                per tile, zero index math; then fused tail in-block
//   bid == 295 : dense consumer: spin ctr, reduce partials, fused tail
// Fragment mappings HW-verified in round 11.
// ---------------------------------------------------------------------------
__global__ __launch_bounds__(512, 2) void mega_k(const unsigned short* __restrict__ w1bf,
                                                 const unsigned short* __restrict__ xtbf,
                                                 const int* __restrict__ cnt,
                                                 const unsigned short* __restrict__ bpk,
                                                 const unsigned short* __restrict__ apk,
                                                 const float* __restrict__ b1,
                                                 const float* __restrict__ g1,
                                                 const float* __restrict__ be1,
                                                 const unsigned short* __restrict__ w2bf,
                                                 const float* __restrict__ b2,
                                                 const float* __restrict__ g2,
                                                 const float* __restrict__ be2,
                                                 float* __restrict__ hpartD,
                                                 int* __restrict__ ctr,
                                                 float* __restrict__ zout) {
    __shared__ __align__(16) char smem[50688];
    __shared__ float rs[8], rss[8];
    float* lhf         = (float*)smem;                      // [32][264] f32
    unsigned short* LA = (unsigned short*)(smem + 33792);   // [32][264] bf16

    const int t = threadIdx.x, bid = blockIdx.x;
    const int w   = t >> 6;            // wave id -> N cols [w*32, w*32+32)
    const int l   = t & 63;
    const int lm  = l & 15;            // intra-tile m/n index
    const int kg  = l >> 4;            // k-group (0..3)
    const int kg8 = kg * 8;

    const bool producer = (bid < DKB_);
    const bool sparse   = (bid >= DKB_ && bid < DKB_ + 255);
    const int g = sparse ? (bid - DKB_) : 255;

    f32x4 acc[2][2];                   // [mt][nt]
#pragma unroll
    for (int mt = 0; mt < 2; ++mt)
#pragma unroll
        for (int nt = 0; nt < 2; ++nt)
#pragma unroll
            for (int r = 0; r < 4; ++r) acc[mt][nt][r] = 0.f;

    if (sparse) {
        // ===== phase A (sparse): packed fragments, pure linear streaming =====
        const int ntiles = min((cnt[g] + 31) >> 5, NTMAX);
        const unsigned short* bp = bpk + (size_t)g * (NTMAX * BPKT_);
        const unsigned short* ap = apk + (size_t)g * (NTMAX * APKT_);
        const int aoff = kg * 128 + lm * 8;
        const int boff0 = ((w * 2 + 0) * 4 + kg) * 128 + lm * 8;
        const int boff1 = ((w * 2 + 1) * 4 + kg) * 128 + lm * 8;

        for (int T = 0; T < ntiles; ++T) {
            short8_t af0 = *(const short8_t*)(ap + T * APKT_ + aoff);
            short8_t af1 = *(const short8_t*)(ap + T * APKT_ + 512 + aoff);
            short8_t bq0 = *(const short8_t*)(bp + T * BPKT_ + boff0);
            short8_t bq1 = *(const short8_t*)(bp + T * BPKT_ + boff1);
            acc[0][0] = __builtin_amdgcn_mfma_f32_16x16x32_bf16(af0, bq0, acc[0][0], 0, 0, 0);
            acc[0][1] = __builtin_amdgcn_mfma_f32_16x16x32_bf16(af0, bq1, acc[0][1], 0, 0, 0);
            acc[1][0] = __builtin_amdgcn_mfma_f32_16x16x32_bf16(af1, bq0, acc[1][0], 0, 0, 0);
            acc[1][1] = __builtin_amdgcn_mfma_f32_16x16x32_bf16(af1, bq1, acc[1][1], 0, 0, 0);
        }

        // -------- + b1, BN1 stats from registers --------
        float b1v0 = b1[w * 32 + lm], b1v1 = b1[w * 32 + 16 + lm];
        float s = 0.f, ss = 0.f;
#pragma unroll
        for (int mt = 0; mt < 2; ++mt)
#pragma unroll
            for (int nt = 0; nt < 2; ++nt)
#pragma unroll
                for (int r = 0; r < 4; ++r) {
                    float v = acc[mt][nt][r] + (nt ? b1v1 : b1v0);
                    acc[mt][nt][r] = v;
                    s += v; ss += v * v;
                }
#pragma unroll
        for (int o = 32; o > 0; o >>= 1) { s += __shfl_down(s, o); ss += __shfl_down(ss, o); }
        if (l == 0) { rs[w] = s; rss[w] = ss; }
        __syncthreads();
        float S = 0.f, SS = 0.f;
#pragma unroll
        for (int j = 0; j < 8; ++j) { S += rs[j]; SS += rss[j]; }
        const float inv = 1.0f / (float)(B_ * HID_);
        float mean = S * inv;
        float var  = SS * inv - mean * mean;      // biased, matches jnp.var
        float sc = g1[g] * rsqrtf(var + EPS_);
        float sh = be1[g] - mean * sc;
        // normalize + ReLU -> LA (bf16)
#pragma unroll
        for (int mt = 0; mt < 2; ++mt)
#pragma unroll
            for (int nt = 0; nt < 2; ++nt)
#pragma unroll
                for (int r = 0; r < 4; ++r) {
                    float y = fmaxf(fmaf(acc[mt][nt][r], sc, sh), 0.f);
                    __hip_bfloat16 hb = __float2bfloat16(y);
                    LA[(mt * 16 + kg * 4 + r) * LAP_ + (w * 32 + nt * 16 + lm)] =
                        *reinterpret_cast<unsigned short*>(&hb);
                }
        __syncthreads();
    } else if (producer) {
        // ===== phase A (dense producer): direct gather, contiguous rows =====
        const int k0 = bid * DCH_;
        for (int base = 0; base < DCH_; base += 32) {
            int nj[8];
#pragma unroll
            for (int j = 0; j < 8; ++j) {
                int kk = base + kg8 + j;
                nj[j] = (kk < DCH_) ? (k0 + kk) : N_;
            }
            short8_t af0, af1, bf0, bf1;
#pragma unroll
            for (int j = 0; j < 8; ++j) {
                const int n = nj[j];
                af0[j] = (short)xtbf[(size_t)n * 32 + lm];
                af1[j] = (short)xtbf[(size_t)n * 32 + 16 + lm];
                bf0[j] = (short)w1bf[(size_t)n * 256 + w * 32 + lm];
                bf1[j] = (short)w1bf[(size_t)n * 256 + w * 32 + 16 + lm];
            }
            acc[0][0] = __builtin_amdgcn_mfma_f32_16x16x32_bf16(af0, bf0, acc[0][0], 0, 0, 0);
            acc[0][1] = __builtin_amdgcn_mfma_f32_16x16x32_bf16(af0, bf1, acc[0][1], 0, 0, 0);
            acc[1][0] = __builtin_amdgcn_mfma_f32_16x16x32_bf16(af1, bf0, acc[1][0], 0, 0, 0);
            acc[1][1] = __builtin_amdgcn_mfma_f32_16x16x32_bf16(af1, bf1, acc[1][1], 0, 0, 0);
        }
        // accs -> lhf -> coalesced hpartD
#pragma unroll
        for (int mt = 0; mt < 2; ++mt)
#pragma unroll
            for (int nt = 0; nt < 2; ++nt)
#pragma unroll
                for (int r = 0; r < 4; ++r)
                    lhf[(mt * 16 + kg * 4 + r) * LAP_ +
                        (w * 32 + nt * 16 + lm)] = acc[mt][nt][r];
        __syncthreads();
#pragma unroll
        for (int it = 0; it < 16; ++it) {
            int id = it * 512 + t;
            hpartD[(size_t)bid * 8192 + id] = lhf[(id >> 8) * LAP_ + (id & 255)];
        }
        __threadfence();
        __syncthreads();
        if (t == 0)
            __hip_atomic_fetch_add(ctr, 1, __ATOMIC_RELEASE,
                                   __HIP_MEMORY_SCOPE_AGENT);
        return;
    } else {
        // ================= dense consumer =================
        if (t == 0) {
            while (__hip_atomic_load(ctr, __ATOMIC_ACQUIRE,
                                     __HIP_MEMORY_SCOPE_AGENT) < DKB_)
                __builtin_amdgcn_s_sleep(1);
            __threadfence();
        }
        __syncthreads();
        float s = 0.f, ss = 0.f;
#pragma unroll
        for (int it = 0; it < 16; ++it) {
            int id = it * 512 + t;
            float v = b1[id & 255];
            for (int kb = 0; kb < DKB_; ++kb)
                v += hpartD[(size_t)kb * 8192 + id];
            lhf[(id >> 8) * LAP_ + (id & 255)] = v;
            s += v; ss += v * v;
        }
#pragma unroll
        for (int o = 32; o > 0; o >>= 1) { s += __shfl_down(s, o); ss += __shfl_down(ss, o); }
        if (l == 0) { rs[w] = s; rss[w] = ss; }
        __syncthreads();
        float S = 0.f, SS = 0.f;
#pragma unroll
        for (int j = 0; j < 8; ++j) { S += rs[j]; SS += rss[j]; }
        const float inv = 1.0f / (float)(B_ * HID_);
        float mean = S * inv;
        float var  = SS * inv - mean * mean;
        float sc = g1[255] * rsqrtf(var + EPS_);
        float sh = be1[255] - mean * sc;
#pragma unroll
        for (int it = 0; it < 16; ++it) {
            int id = it * 512 + t;
            float v = lhf[(id >> 8) * LAP_ + (id & 255)];
            float y = fmaxf(fmaf(v, sc, sh), 0.f);
            __hip_bfloat16 hb = __float2bfloat16(y);
            LA[(id >> 8) * LAP_ + (id & 255)] =
                *reinterpret_cast<unsigned short*>(&hb);
        }
        __syncthreads();
    }

    // ================= GEMM2 via MFMA + BN2 + ReLU =================
    f32x4 a2[2][2];
#pragma unroll
    for (int mt = 0; mt < 2; ++mt)
#pragma unroll
        for (int nt = 0; nt < 2; ++nt)
#pragma unroll
            for (int r = 0; r < 4; ++r) a2[mt][nt][r] = 0.f;

#pragma unroll
    for (int ks = 0; ks < 8; ++ks) {
        short8_t af[2], bfm[2];
#pragma unroll
        for (int mt = 0; mt < 2; ++mt)
            af[mt] = *(const short8_t*)&LA[(mt * 16 + lm) * LAP_ + ks * 32 + kg8];
#pragma unroll
        for (int nt = 0; nt < 2; ++nt)
            bfm[nt] = *(const short8_t*)&w2bf[(size_t)(w * 32 + nt * 16 + lm) * 256 +
                                              ks * 32 + kg8];
#pragma unroll
        for (int mt = 0; mt < 2; ++mt)
#pragma unroll
            for (int nt = 0; nt < 2; ++nt)
                a2[mt][nt] = __builtin_amdgcn_mfma_f32_16x16x32_bf16(
                    af[mt], bfm[nt], a2[mt][nt], 0, 0, 0);
    }

    float b2v0 = b2[w * 32 + lm], b2v1 = b2[w * 32 + 16 + lm];
    float s2 = 0.f, ss2 = 0.f;
#pragma unroll
    for (int mt = 0; mt < 2; ++mt)
#pragma unroll
        for (int nt = 0; nt < 2; ++nt)
#pragma unroll
            for (int r = 0; r < 4; ++r) {
                float v = a2[mt][nt][r] + (nt ? b2v1 : b2v0);
                a2[mt][nt][r] = v;
                s2 += v; ss2 += v * v;
            }
#pragma unroll
    for (int o = 32; o > 0; o >>= 1) { s2 += __shfl_down(s2, o); ss2 += __shfl_down(ss2, o); }
    if (l == 0) { rs[w] = s2; rss[w] = ss2; }   // safe: prior rs reads barrier'd
    __syncthreads();
    float S2 = 0.f, SS2 = 0.f;
#pragma unroll
    for (int j = 0; j < 8; ++j) { S2 += rs[j]; SS2 += rss[j]; }
    const float inv = 1.0f / (float)(B_ * HID_);
    float mean2 = S2 * inv;
    float var2  = SS2 * inv - mean2 * mean2;
    float sc2 = g2[g] * rsqrtf(var2 + EPS_);
    float sh2 = be2[g] - mean2 * sc2;

#pragma unroll
    for (int mt = 0; mt < 2; ++mt)
#pragma unroll
        for (int nt = 0; nt < 2; ++nt)
#pragma unroll
            for (int r = 0; r < 4; ++r) {
                int b = mt * 16 + kg * 4 + r;
                int z = w * 32 + nt * 16 + lm;
                zout[((size_t)b * G_ + g) * 256 + z] =
                    fmaxf(fmaf(a2[mt][nt][r], sc2, sh2), 0.f);
            }
}

// ---------------------------------------------------------------------------
extern "C" void kernel_launch(void* const* d_in, const int* in_sizes, int n_in,
                              void* d_out, int out_size, void* d_ws, size_t ws_size,
                              hipStream_t stream) {
    const float* x    = (const float*)d_in[0];
    const float* mask = (const float*)d_in[1];
    const float* W1   = (const float*)d_in[2];
    const float* b1   = (const float*)d_in[3];
    const float* g1   = (const float*)d_in[4];
    const float* be1  = (const float*)d_in[5];
    const float* W2   = (const float*)d_in[6];
    const float* b2   = (const float*)d_in[7];
    const float* g2   = (const float*)d_in[8];
    const float* be2  = (const float*)d_in[9];
    float* out = (float*)d_out;

    char* ws = (char*)d_ws;
    size_t off = 0;
    auto take = [&](size_t bytes) {
        char* p = ws + off;
        off = (off + bytes + 255) & ~(size_t)255;
        return p;
    };
    __hip_bfloat16* w1bf = (__hip_bfloat16*)take((size_t)(N_ + 1) * HID_ * 2); // (N+1,HID)
    __hip_bfloat16* xtbf = (__hip_bfloat16*)take((size_t)(N_ + 1) * B_ * 2);   // (N+1,B)
    __hip_bfloat16* w2bf = (__hip_bfloat16*)take((size_t)HID_ * HID_ * 2);     // (Z,HID)
    float* hpartD        = (float*)take((size_t)DKB_ * B_ * HID_ * 4);
    int* cnt             = (int*)take((size_t)G_ * 4);
    unsigned short* idx  = (unsigned short*)take((size_t)G_ * N_ * 2);
    int* ctr             = (int*)take(256);
    unsigned short* bpk  = (unsigned short*)take((size_t)255 * NTMAX * BPKT_ * 2); // 41.8MB
    unsigned short* apk  = (unsigned short*)take((size_t)255 * NTMAX * APKT_ * 2); // 5.2MB

    prep_k<<<PREP_GRID, 256, 0, stream>>>(W1, x, W2, mask, w1bf, xtbf, w2bf,
                                          cnt, idx, ctr);
    pack_k<<<255, 256, 0, stream>>>(cnt, idx, (const uint4*)w1bf,
                                    (const unsigned short*)xtbf, bpk, apk);
    mega_k<<<MEGA_GRID, 512, 0, stream>>>((const unsigned short*)w1bf,
                                          (const unsigned short*)xtbf,
                                          cnt, bpk, apk, b1, g1, be1,
                                          (const unsigned short*)w2bf,
                                          b2, g2, be2,
                                          hpartD, ctr, out);
}

// Round 18
// 58.416 us; speedup vs baseline: 1.6863x; 1.6863x over previous
//
#include <hip/hip_runtime.h>
#include <hip/hip_bf16.h>

#define B_    32
#define N_    10000
#define G_    256
#define HID_  256
#define EPS_  1e-5f

typedef __attribute__((ext_vector_type(8))) short short8_t;
typedef __attribute__((ext_vector_type(4))) float f32x4;

// prep_k grid segmentation
#define TB_W1  2504            // W1 transpose->bf16: 313 x 8 tiles
#define TB_X   313             // x transpose->bf16: 32 x 10000
#define NB_W2C 64              // W2 -> bf16 cast (no transpose)
#define NB_CMP 256             // mask compaction, one block per g
#define PREP_GRID (TB_W1 + TB_X + NB_W2C + NB_CMP + 1)   // 3138 (+1 zero-row)

#define DKB_  16               // dense-group split-K producer blocks
#define DCH_  625              // genes per dense chunk (16*625 = 10000)
#define MEGA_GRID (DKB_ + 255 + 1)   // 272

#define LAP_  264              // LA / lhf pitch in elements (16B-aligned rows)

// ---------------------------------------------------------------------------
// Tiled transpose helper (f32 -> bf16).
// ---------------------------------------------------------------------------
__device__ inline void transpose_tile_bf16(const float* __restrict__ src,
                                           __hip_bfloat16* __restrict__ dst,
                                           int R, int C, int bx, int by, int t,
                                           float (*tile)[33]) {
    int tx = t & 31, ty = t >> 5;      // 32 x 8
    int c0 = bx * 32, r0 = by * 32;
#pragma unroll
    for (int j = 0; j < 4; ++j) {
        int r = r0 + ty + j * 8, c = c0 + tx;
        if (r < R && c < C) tile[ty + j * 8][tx] = src[(size_t)r * C + c];
    }
    __syncthreads();
#pragma unroll
    for (int j = 0; j < 4; ++j) {
        int c = c0 + ty + j * 8, r = r0 + tx;
        if (r < R && c < C)
            dst[(size_t)c * R + r] = __float2bfloat16(tile[tx][ty + j * 8]);
    }
}

// ---------------------------------------------------------------------------
// Fused prep: W1/x -> bf16 transposes, W2 -> bf16 cast, compaction, zero-row.
// ---------------------------------------------------------------------------
__global__ __launch_bounds__(256) void prep_k(const float* __restrict__ W1,
                                              const float* __restrict__ x,
                                              const float* __restrict__ W2,
                                              const float* __restrict__ mask,
                                              __hip_bfloat16* __restrict__ w1bf,
                                              __hip_bfloat16* __restrict__ xtbf,
                                              __hip_bfloat16* __restrict__ w2bf,
                                              int* __restrict__ cnt,
                                              unsigned short* __restrict__ idx,
                                              int* __restrict__ ctr) {
    __shared__ float tile[32][33];
    __shared__ int c;
    int bid = blockIdx.x, t = threadIdx.x;

    if (bid == 0 && t == 0) *ctr = 0;  // reset mega_k producer counter

    if (bid < TB_W1) {
        transpose_tile_bf16(W1, w1bf, HID_, N_, bid % 313, bid / 313, t, tile);
    } else if (bid < TB_W1 + TB_X) {
        transpose_tile_bf16(x, xtbf, B_, N_, bid - TB_W1, 0, t, tile);
    } else if (bid < TB_W1 + TB_X + NB_W2C) {
        int b = bid - (TB_W1 + TB_X);
#pragma unroll
        for (int j = 0; j < 4; ++j) {
            int i = b * 1024 + j * 256 + t;
            w2bf[i] = __float2bfloat16(W2[i]);
        }
    } else if (bid < TB_W1 + TB_X + NB_W2C + NB_CMP) {
        int g = bid - (TB_W1 + TB_X + NB_W2C);
        if (g == 255) return;              // dense group: contiguous, no list
        if (t == 0) c = 0;
        __syncthreads();
        for (int n = t; n < N_; n += 256) {
            if (mask[(size_t)g * N_ + n] != 0.0f) {
                int p = atomicAdd(&c, 1);          // LDS atomic only
                idx[(size_t)g * N_ + p] = (unsigned short)n;
            }
        }
        __syncthreads();
        if (t == 0) cnt[g] = c;
    } else {
        // zero row N_ of w1bf and xtbf (pad-gene target: contributes 0)
        w1bf[(size_t)N_ * 256 + t] = __float2bfloat16(0.f);
        if (t < 32) xtbf[(size_t)N_ * 32 + t] = __float2bfloat16(0.f);
    }
}

// ---------------------------------------------------------------------------
// MEGA kernel, MFMA + direct-global fragment gather (no phase-A LDS/barriers).
//   bid <  16  : dense producer (group 255, 625 genes) -> hpartD (f32), ctr++
//   bid 16..270: sparse group g = bid-16, fully fused in-block
//   bid == 271 : dense consumer: spin ctr, MLP-reduce partials, fused tail
// 512 threads = 8 waves. Wave w owns output cols [w*32, w*32+32) (2 N-tiles)
// x both M-tiles (rows 0..31). Fragments (HW-verified in round 11):
//   A: lane l -> A[l&15][(l>>4)*8+j]       (A[b][k] = x_bf16[gene_k][b])
//   B: lane l -> B[(l>>4)*8+j][l&15]       (B[k][h] = W1_bf16[gene_k][h])
//   C/D: lane l reg r -> D[(l>>4)*4+r][l&15]
// Tail genes map to zero-row N_ (branchless select) -> no remainder code.
// ---------------------------------------------------------------------------
__global__ __launch_bounds__(512, 2) void mega_k(const unsigned short* __restrict__ w1bf,
                                                 const unsigned short* __restrict__ xtbf,
                                                 const int* __restrict__ cnt,
                                                 const unsigned short* __restrict__ idx,
                                                 const float* __restrict__ b1,
                                                 const float* __restrict__ g1,
                                                 const float* __restrict__ be1,
                                                 const unsigned short* __restrict__ w2bf,
                                                 const float* __restrict__ b2,
                                                 const float* __restrict__ g2,
                                                 const float* __restrict__ be2,
                                                 float* __restrict__ hpartD,
                                                 int* __restrict__ ctr,
                                                 float* __restrict__ zout) {
    __shared__ __align__(16) char smem[50688];
    __shared__ float rs[8], rss[8];
    float* lhf         = (float*)smem;                      // [32][264] f32
    unsigned short* LA = (unsigned short*)(smem + 33792);   // [32][264] bf16

    const int t = threadIdx.x, bid = blockIdx.x;
    const int w   = t >> 6;            // wave id -> N cols [w*32, w*32+32)
    const int l   = t & 63;
    const int lm  = l & 15;            // intra-tile m/n index
    const int kg  = l >> 4;            // k-group (0..3)
    const int kg8 = kg * 8;

    const bool producer = (bid < DKB_);
    const bool sparse   = (bid >= DKB_ && bid < DKB_ + 255);
    const int g = sparse ? (bid - DKB_) : 255;

    f32x4 acc[2][2];                   // [mt][nt]
#pragma unroll
    for (int mt = 0; mt < 2; ++mt)
#pragma unroll
        for (int nt = 0; nt < 2; ++nt)
#pragma unroll
            for (int r = 0; r < 4; ++r) acc[mt][nt][r] = 0.f;

    if (producer || sparse) {
        // ========== phase A: GEMM1, direct-global MFMA fragments ==========
        const int k0   = producer ? bid * DCH_ : 0;        // absolute gene base
        const int kend = producer ? DCH_ : cnt[g];         // relative count
        const unsigned short* lp = idx + (size_t)g * N_;

        for (int base = 0; base < kend; base += 32) {
            int nj[8];
            if (sparse) {
                uint4 ip = *(const uint4*)(lp + base + kg8);   // 16B, aligned
                unsigned int uu[4] = {ip.x, ip.y, ip.z, ip.w};
#pragma unroll
                for (int j = 0; j < 8; ++j) {
                    int kk = base + kg8 + j;
                    int nv = (int)((uu[j >> 1] >> ((j & 1) * 16)) & 0xffffu);
                    nj[j] = (kk < kend) ? nv : N_;             // pad -> zero row
                }
            } else {
#pragma unroll
                for (int j = 0; j < 8; ++j) {
                    int kk = base + kg8 + j;
                    nj[j] = (kk < kend) ? (k0 + kk) : N_;
                }
            }
            short8_t af0, af1, bf0, bf1;
#pragma unroll
            for (int j = 0; j < 8; ++j) {
                const int n = nj[j];
                af0[j] = (short)xtbf[(size_t)n * 32 + lm];             // A[b][k]
                af1[j] = (short)xtbf[(size_t)n * 32 + 16 + lm];
                bf0[j] = (short)w1bf[(size_t)n * 256 + w * 32 + lm];   // B[k][h]
                bf1[j] = (short)w1bf[(size_t)n * 256 + w * 32 + 16 + lm];
            }
            acc[0][0] = __builtin_amdgcn_mfma_f32_16x16x32_bf16(af0, bf0, acc[0][0], 0, 0, 0);
            acc[0][1] = __builtin_amdgcn_mfma_f32_16x16x32_bf16(af0, bf1, acc[0][1], 0, 0, 0);
            acc[1][0] = __builtin_amdgcn_mfma_f32_16x16x32_bf16(af1, bf0, acc[1][0], 0, 0, 0);
            acc[1][1] = __builtin_amdgcn_mfma_f32_16x16x32_bf16(af1, bf1, acc[1][1], 0, 0, 0);
        }

        if (producer) {
            // accs -> lhf -> coalesced hpartD
#pragma unroll
            for (int mt = 0; mt < 2; ++mt)
#pragma unroll
                for (int nt = 0; nt < 2; ++nt)
#pragma unroll
                    for (int r = 0; r < 4; ++r)
                        lhf[(mt * 16 + kg * 4 + r) * LAP_ +
                            (w * 32 + nt * 16 + lm)] = acc[mt][nt][r];
            __syncthreads();
#pragma unroll
            for (int it = 0; it < 16; ++it) {
                int id = it * 512 + t;
                hpartD[(size_t)bid * 8192 + id] = lhf[(id >> 8) * LAP_ + (id & 255)];
            }
            __threadfence();
            __syncthreads();
            if (t == 0)
                __hip_atomic_fetch_add(ctr, 1, __ATOMIC_RELEASE,
                                       __HIP_MEMORY_SCOPE_AGENT);
            return;
        }

        // -------- sparse: + b1, BN1 stats from registers --------
        float b1v0 = b1[w * 32 + lm], b1v1 = b1[w * 32 + 16 + lm];
        float s = 0.f, ss = 0.f;
#pragma unroll
        for (int mt = 0; mt < 2; ++mt)
#pragma unroll
            for (int nt = 0; nt < 2; ++nt)
#pragma unroll
                for (int r = 0; r < 4; ++r) {
                    float v = acc[mt][nt][r] + (nt ? b1v1 : b1v0);
                    acc[mt][nt][r] = v;
                    s += v; ss += v * v;
                }
#pragma unroll
        for (int o = 32; o > 0; o >>= 1) { s += __shfl_down(s, o); ss += __shfl_down(ss, o); }
        if (l == 0) { rs[w] = s; rss[w] = ss; }
        __syncthreads();
        float S = 0.f, SS = 0.f;
#pragma unroll
        for (int j = 0; j < 8; ++j) { S += rs[j]; SS += rss[j]; }
        const float inv = 1.0f / (float)(B_ * HID_);
        float mean = S * inv;
        float var  = SS * inv - mean * mean;      // biased, matches jnp.var
        float sc = g1[g] * rsqrtf(var + EPS_);
        float sh = be1[g] - mean * sc;
        // normalize + ReLU -> LA (bf16)
#pragma unroll
        for (int mt = 0; mt < 2; ++mt)
#pragma unroll
            for (int nt = 0; nt < 2; ++nt)
#pragma unroll
                for (int r = 0; r < 4; ++r) {
                    float y = fmaxf(fmaf(acc[mt][nt][r], sc, sh), 0.f);
                    __hip_bfloat16 hb = __float2bfloat16(y);
                    LA[(mt * 16 + kg * 4 + r) * LAP_ + (w * 32 + nt * 16 + lm)] =
                        *reinterpret_cast<unsigned short*>(&hb);
                }
        __syncthreads();
    } else {
        // ================= dense consumer (MLP-friendly reduce) =============
        if (t == 0) {
            while (__hip_atomic_load(ctr, __ATOMIC_ACQUIRE,
                                     __HIP_MEMORY_SCOPE_AGENT) < DKB_)
                __builtin_amdgcn_s_sleep(1);
            __threadfence();
        }
        __syncthreads();
        float s = 0.f, ss = 0.f;
#pragma unroll
        for (int it = 0; it < 16; ++it) {
            int id = it * 512 + t;
            float p0 = 0.f, p1 = 0.f, p2 = 0.f, p3 = 0.f;
#pragma unroll
            for (int kb = 0; kb < DKB_; kb += 4) {   // 16 independent loads
                p0 += hpartD[(size_t)(kb + 0) * 8192 + id];
                p1 += hpartD[(size_t)(kb + 1) * 8192 + id];
                p2 += hpartD[(size_t)(kb + 2) * 8192 + id];
                p3 += hpartD[(size_t)(kb + 3) * 8192 + id];
            }
            float v = b1[id & 255] + ((p0 + p1) + (p2 + p3));
            lhf[(id >> 8) * LAP_ + (id & 255)] = v;
            s += v; ss += v * v;
        }
#pragma unroll
        for (int o = 32; o > 0; o >>= 1) { s += __shfl_down(s, o); ss += __shfl_down(ss, o); }
        if (l == 0) { rs[w] = s; rss[w] = ss; }
        __syncthreads();
        float S = 0.f, SS = 0.f;
#pragma unroll
        for (int j = 0; j < 8; ++j) { S += rs[j]; SS += rss[j]; }
        const float inv = 1.0f / (float)(B_ * HID_);
        float mean = S * inv;
        float var  = SS * inv - mean * mean;
        float sc = g1[255] * rsqrtf(var + EPS_);
        float sh = be1[255] - mean * sc;
#pragma unroll
        for (int it = 0; it < 16; ++it) {
            int id = it * 512 + t;
            float v = lhf[(id >> 8) * LAP_ + (id & 255)];
            float y = fmaxf(fmaf(v, sc, sh), 0.f);
            __hip_bfloat16 hb = __float2bfloat16(y);
            LA[(id >> 8) * LAP_ + (id & 255)] =
                *reinterpret_cast<unsigned short*>(&hb);
        }
        __syncthreads();
    }

    // ================= GEMM2 via MFMA + BN2 + ReLU =================
    f32x4 a2[2][2];
#pragma unroll
    for (int mt = 0; mt < 2; ++mt)
#pragma unroll
        for (int nt = 0; nt < 2; ++nt)
#pragma unroll
            for (int r = 0; r < 4; ++r) a2[mt][nt][r] = 0.f;

#pragma unroll
    for (int ks = 0; ks < 8; ++ks) {
        short8_t af[2], bfm[2];
#pragma unroll
        for (int mt = 0; mt < 2; ++mt)
            af[mt] = *(const short8_t*)&LA[(mt * 16 + lm) * LAP_ + ks * 32 + kg8];
#pragma unroll
        for (int nt = 0; nt < 2; ++nt)
            bfm[nt] = *(const short8_t*)&w2bf[(size_t)(w * 32 + nt * 16 + lm) * 256 +
                                              ks * 32 + kg8];
#pragma unroll
        for (int mt = 0; mt < 2; ++mt)
#pragma unroll
            for (int nt = 0; nt < 2; ++nt)
                a2[mt][nt] = __builtin_amdgcn_mfma_f32_16x16x32_bf16(
                    af[mt], bfm[nt], a2[mt][nt], 0, 0, 0);
    }

    float b2v0 = b2[w * 32 + lm], b2v1 = b2[w * 32 + 16 + lm];
    float s2 = 0.f, ss2 = 0.f;
#pragma unroll
    for (int mt = 0; mt < 2; ++mt)
#pragma unroll
        for (int nt = 0; nt < 2; ++nt)
#pragma unroll
            for (int r = 0; r < 4; ++r) {
                float v = a2[mt][nt][r] + (nt ? b2v1 : b2v0);
                a2[mt][nt][r] = v;
                s2 += v; ss2 += v * v;
            }
#pragma unroll
    for (int o = 32; o > 0; o >>= 1) { s2 += __shfl_down(s2, o); ss2 += __shfl_down(ss2, o); }
    if (l == 0) { rs[w] = s2; rss[w] = ss2; }   // safe: prior rs reads barrier'd
    __syncthreads();
    float S2 = 0.f, SS2 = 0.f;
#pragma unroll
    for (int j = 0; j < 8; ++j) { S2 += rs[j]; SS2 += rss[j]; }
    const float inv = 1.0f / (float)(B_ * HID_);
    float mean2 = S2 * inv;
    float var2  = SS2 * inv - mean2 * mean2;
    float sc2 = g2[g] * rsqrtf(var2 + EPS_);
    float sh2 = be2[g] - mean2 * sc2;

#pragma unroll
    for (int mt = 0; mt < 2; ++mt)
#pragma unroll
        for (int nt = 0; nt < 2; ++nt)
#pragma unroll
            for (int r = 0; r < 4; ++r) {
                int b = mt * 16 + kg * 4 + r;
                int z = w * 32 + nt * 16 + lm;
                zout[((size_t)b * G_ + g) * 256 + z] =
                    fmaxf(fmaf(a2[mt][nt][r], sc2, sh2), 0.f);
            }
}

// ---------------------------------------------------------------------------
extern "C" void kernel_launch(void* const* d_in, const int* in_sizes, int n_in,
                              void* d_out, int out_size, void* d_ws, size_t ws_size,
                              hipStream_t stream) {
    const float* x    = (const float*)d_in[0];
    const float* mask = (const float*)d_in[1];
    const float* W1   = (const float*)d_in[2];
    const float* b1   = (const float*)d_in[3];
    const float* g1   = (const float*)d_in[4];
    const float* be1  = (const float*)d_in[5];
    const float* W2   = (const float*)d_in[6];
    const float* b2   = (const float*)d_in[7];
    const float* g2   = (const float*)d_in[8];
    const float* be2  = (const float*)d_in[9];
    float* out = (float*)d_out;

    char* ws = (char*)d_ws;
    size_t off = 0;
    auto take = [&](size_t bytes) {
        char* p = ws + off;
        off = (off + bytes + 255) & ~(size_t)255;
        return p;
    };
    __hip_bfloat16* w1bf = (__hip_bfloat16*)take((size_t)(N_ + 1) * HID_ * 2); // (N+1,HID)
    __hip_bfloat16* xtbf = (__hip_bfloat16*)take((size_t)(N_ + 1) * B_ * 2);   // (N+1,B)
    __hip_bfloat16* w2bf = (__hip_bfloat16*)take((size_t)HID_ * HID_ * 2);     // (Z,HID)
    float* hpartD        = (float*)take((size_t)DKB_ * B_ * HID_ * 4);
    int* cnt             = (int*)take((size_t)G_ * 4);
    unsigned short* idx  = (unsigned short*)take((size_t)G_ * N_ * 2);
    int* ctr             = (int*)take(256);

    prep_k<<<PREP_GRID, 256, 0, stream>>>(W1, x, W2, mask, w1bf, xtbf, w2bf,
                                          cnt, idx, ctr);
    mega_k<<<MEGA_GRID, 512, 0, stream>>>((const unsigned short*)w1bf,
                                          (const unsigned short*)xtbf,
                                          cnt, idx, b1, g1, be1,
                                          (const unsigned short*)w2bf,
                                          b2, g2, be2,
                                          hpartD, ctr, out);
}

// Round 19
// 53.534 us; speedup vs baseline: 1.8401x; 1.0912x over previous
//
#include <hip/hip_runtime.h>
#include <hip/hip_bf16.h>

#define B_    32
#define N_    10000
#define G_    256
#define HID_  256
#define EPS_  1e-5f

typedef __attribute__((ext_vector_type(8))) short short8_t;
typedef __attribute__((ext_vector_type(4))) float f32x4;

// prep_k grid segmentation
#define TB_W1  2504            // W1 transpose->bf16: 313 x 8 tiles
#define TB_X   313             // x transpose->bf16: 32 x 10000
#define NB_W2C 64              // W2 -> bf16 cast (no transpose)
#define NB_CMP 256             // mask compaction, one block per g
#define PREP_GRID (TB_W1 + TB_X + NB_W2C + NB_CMP + 1)   // 3138 (+1 zero-row)

#define DKB_  16               // dense-group split-K producer blocks (mult of 8)
#define DCH_  625              // genes per dense chunk (16*625 = 10000)
#define G1_GRID (DKB_ + 255)   // 271: dense producers first, then sparse
                               // sparse g at bid 16+g == g (mod 8) -> same XCD
                               // as fused_k's block g => h[g] L2-local.

#define LAP_  264              // LA pitch in elements (16B-aligned rows)

// ---------------------------------------------------------------------------
// Tiled transpose helper (f32 -> bf16).
// ---------------------------------------------------------------------------
__device__ inline void transpose_tile_bf16(const float* __restrict__ src,
                                           __hip_bfloat16* __restrict__ dst,
                                           int R, int C, int bx, int by, int t,
                                           float (*tile)[33]) {
    int tx = t & 31, ty = t >> 5;      // 32 x 8
    int c0 = bx * 32, r0 = by * 32;
#pragma unroll
    for (int j = 0; j < 4; ++j) {
        int r = r0 + ty + j * 8, c = c0 + tx;
        if (r < R && c < C) tile[ty + j * 8][tx] = src[(size_t)r * C + c];
    }
    __syncthreads();
#pragma unroll
    for (int j = 0; j < 4; ++j) {
        int c = c0 + ty + j * 8, r = r0 + tx;
        if (r < R && c < C)
            dst[(size_t)c * R + r] = __float2bfloat16(tile[tx][ty + j * 8]);
    }
}

// ---------------------------------------------------------------------------
// Fused prep: W1/x -> bf16 transposes, W2 -> bf16 cast, compaction, zero-row.
// ---------------------------------------------------------------------------
__global__ __launch_bounds__(256) void prep_k(const float* __restrict__ W1,
                                              const float* __restrict__ x,
                                              const float* __restrict__ W2,
                                              const float* __restrict__ mask,
                                              __hip_bfloat16* __restrict__ w1bf,
                                              __hip_bfloat16* __restrict__ xtbf,
                                              __hip_bfloat16* __restrict__ w2bf,
                                              int* __restrict__ cnt,
                                              unsigned short* __restrict__ idx) {
    __shared__ float tile[32][33];
    __shared__ int c;
    int bid = blockIdx.x, t = threadIdx.x;

    if (bid < TB_W1) {
        transpose_tile_bf16(W1, w1bf, HID_, N_, bid % 313, bid / 313, t, tile);
    } else if (bid < TB_W1 + TB_X) {
        transpose_tile_bf16(x, xtbf, B_, N_, bid - TB_W1, 0, t, tile);
    } else if (bid < TB_W1 + TB_X + NB_W2C) {
        int b = bid - (TB_W1 + TB_X);
#pragma unroll
        for (int j = 0; j < 4; ++j) {
            int i = b * 1024 + j * 256 + t;
            w2bf[i] = __float2bfloat16(W2[i]);
        }
    } else if (bid < TB_W1 + TB_X + NB_W2C + NB_CMP) {
        int g = bid - (TB_W1 + TB_X + NB_W2C);
        if (g == 255) return;              // dense group: contiguous, no list
        if (t == 0) c = 0;
        __syncthreads();
        for (int n = t; n < N_; n += 256) {
            if (mask[(size_t)g * N_ + n] != 0.0f) {
                int p = atomicAdd(&c, 1);          // LDS atomic only
                idx[(size_t)g * N_ + p] = (unsigned short)n;
            }
        }
        __syncthreads();
        if (t == 0) cnt[g] = c;
    } else {
        // zero row N_ of w1bf and xtbf (pad-gene target: contributes 0)
        w1bf[(size_t)N_ * 256 + t] = __float2bfloat16(0.f);
        if (t < 32) xtbf[(size_t)N_ * 32 + t] = __float2bfloat16(0.f);
    }
}

// ---------------------------------------------------------------------------
// GEMM1 via MFMA, direct-global fragment gather. ZERO LDS, no sync objects.
//   bid <  16  : dense producer (group 255, 625 genes) -> hpartD[bid]
//   bid 16..270: sparse group g = bid-16 -> h[g] (+b1), straight from regs
// 512 threads = 8 waves. Wave w owns output cols [w*32, w*32+32).
// Fragments (HW-verified round 11):
//   A: lane l -> A[l&15][(l>>4)*8+j]       (A[b][k] = x_bf16[gene_k][b])
//   B: lane l -> B[(l>>4)*8+j][l&15]       (B[k][h] = W1_bf16[gene_k][h])
//   C/D: lane l reg r -> D[(l>>4)*4+r][l&15]  => global write row*256+col
//        lands as plain [b][c] row-major (4 x 64B segments per store inst).
// Tail genes -> zero-row N_ (branchless).
// ---------------------------------------------------------------------------
__global__ __launch_bounds__(512, 2) void gemm1_k(const unsigned short* __restrict__ w1bf,
                                                  const unsigned short* __restrict__ xtbf,
                                                  const int* __restrict__ cnt,
                                                  const unsigned short* __restrict__ idx,
                                                  const float* __restrict__ b1,
                                                  float* __restrict__ h,
                                                  float* __restrict__ hpartD) {
    const int t = threadIdx.x, bid = blockIdx.x;
    const int w   = t >> 6;
    const int l   = t & 63;
    const int lm  = l & 15;
    const int kg  = l >> 4;
    const int kg8 = kg * 8;

    const bool producer = (bid < DKB_);
    const int g = producer ? 255 : (bid - DKB_);

    f32x4 acc[2][2];
#pragma unroll
    for (int mt = 0; mt < 2; ++mt)
#pragma unroll
        for (int nt = 0; nt < 2; ++nt)
#pragma unroll
            for (int r = 0; r < 4; ++r) acc[mt][nt][r] = 0.f;

    const int k0   = producer ? bid * DCH_ : 0;
    const int kend = producer ? DCH_ : cnt[g];
    const unsigned short* lp = idx + (size_t)g * N_;

    for (int base = 0; base < kend; base += 32) {
        int nj[8];
        if (!producer) {
            uint4 ip = *(const uint4*)(lp + base + kg8);   // 16B, aligned
            unsigned int uu[4] = {ip.x, ip.y, ip.z, ip.w};
#pragma unroll
            for (int j = 0; j < 8; ++j) {
                int kk = base + kg8 + j;
                int nv = (int)((uu[j >> 1] >> ((j & 1) * 16)) & 0xffffu);
                nj[j] = (kk < kend) ? nv : N_;             // pad -> zero row
            }
        } else {
#pragma unroll
            for (int j = 0; j < 8; ++j) {
                int kk = base + kg8 + j;
                nj[j] = (kk < kend) ? (k0 + kk) : N_;
            }
        }
        short8_t af0, af1, bf0, bf1;
#pragma unroll
        for (int j = 0; j < 8; ++j) {
            const int n = nj[j];
            af0[j] = (short)xtbf[(size_t)n * 32 + lm];             // A[b][k]
            af1[j] = (short)xtbf[(size_t)n * 32 + 16 + lm];
            bf0[j] = (short)w1bf[(size_t)n * 256 + w * 32 + lm];   // B[k][h]
            bf1[j] = (short)w1bf[(size_t)n * 256 + w * 32 + 16 + lm];
        }
        acc[0][0] = __builtin_amdgcn_mfma_f32_16x16x32_bf16(af0, bf0, acc[0][0], 0, 0, 0);
        acc[0][1] = __builtin_amdgcn_mfma_f32_16x16x32_bf16(af0, bf1, acc[0][1], 0, 0, 0);
        acc[1][0] = __builtin_amdgcn_mfma_f32_16x16x32_bf16(af1, bf0, acc[1][0], 0, 0, 0);
        acc[1][1] = __builtin_amdgcn_mfma_f32_16x16x32_bf16(af1, bf1, acc[1][1], 0, 0, 0);
    }

    if (producer) {
        float* dst = hpartD + (size_t)bid * 8192;
#pragma unroll
        for (int mt = 0; mt < 2; ++mt)
#pragma unroll
            for (int nt = 0; nt < 2; ++nt)
#pragma unroll
                for (int r = 0; r < 4; ++r)
                    dst[(mt * 16 + kg * 4 + r) * 256 + (w * 32 + nt * 16 + lm)] =
                        acc[mt][nt][r];
    } else {
        float b1v0 = b1[w * 32 + lm], b1v1 = b1[w * 32 + 16 + lm];
        float* dst = h + (size_t)g * 8192;
#pragma unroll
        for (int mt = 0; mt < 2; ++mt)
#pragma unroll
            for (int nt = 0; nt < 2; ++nt)
#pragma unroll
                for (int r = 0; r < 4; ++r)
                    dst[(mt * 16 + kg * 4 + r) * 256 + (w * 32 + nt * 16 + lm)] =
                        acc[mt][nt][r] + (nt ? b1v1 : b1v0);
    }
}

// ---------------------------------------------------------------------------
// Dense-group reduction: h[255][i] = b1 + sum over 16 chunks (MLP-friendly).
// ---------------------------------------------------------------------------
__global__ __launch_bounds__(256) void reduce_k(const float* __restrict__ hpartD,
                                                const float* __restrict__ b1,
                                                float* __restrict__ h) {
    int i = blockIdx.x * 256 + threadIdx.x;   // 0..8191
    float p0 = 0.f, p1 = 0.f, p2 = 0.f, p3 = 0.f;
#pragma unroll
    for (int kb = 0; kb < DKB_; kb += 4) {
        p0 += hpartD[(size_t)(kb + 0) * 8192 + i];
        p1 += hpartD[(size_t)(kb + 1) * 8192 + i];
        p2 += hpartD[(size_t)(kb + 2) * 8192 + i];
        p3 += hpartD[(size_t)(kb + 3) * 8192 + i];
    }
    h[(size_t)255 * 8192 + i] = b1[i & 255] + ((p0 + p1) + (p2 + p3));
}

// ---------------------------------------------------------------------------
// Fused tail: h[g] -> BN1+ReLU -> GEMM2 (MFMA) -> BN2+ReLU -> out.
// One block per group, 512 threads. h loads go straight into the C/D
// register layout (4 x 64B segments per load inst). LDS = LA only (17KB).
// ---------------------------------------------------------------------------
__global__ __launch_bounds__(512, 2) void fused_k(const float* __restrict__ h,
                                                  const float* __restrict__ g1,
                                                  const float* __restrict__ be1,
                                                  const unsigned short* __restrict__ w2bf,
                                                  const float* __restrict__ b2,
                                                  const float* __restrict__ g2,
                                                  const float* __restrict__ be2,
                                                  float* __restrict__ zout) {
    __shared__ unsigned short LA[32 * LAP_];   // 16.9 KB
    __shared__ float rs[8], rss[8];

    const int t = threadIdx.x, g = blockIdx.x;
    const int w   = t >> 6;
    const int l   = t & 63;
    const int lm  = l & 15;
    const int kg  = l >> 4;
    const int kg8 = kg * 8;

    // ---- load h[g] into C/D-layout registers, accumulate BN1 stats ----
    const float* hg = h + (size_t)g * 8192;
    f32x4 acc[2][2];
    float s = 0.f, ss = 0.f;
#pragma unroll
    for (int mt = 0; mt < 2; ++mt)
#pragma unroll
        for (int nt = 0; nt < 2; ++nt)
#pragma unroll
            for (int r = 0; r < 4; ++r) {
                float v = hg[(mt * 16 + kg * 4 + r) * 256 + (w * 32 + nt * 16 + lm)];
                acc[mt][nt][r] = v;
                s += v; ss += v * v;
            }
#pragma unroll
    for (int o = 32; o > 0; o >>= 1) { s += __shfl_down(s, o); ss += __shfl_down(ss, o); }
    if (l == 0) { rs[w] = s; rss[w] = ss; }
    __syncthreads();
    float S = 0.f, SS = 0.f;
#pragma unroll
    for (int j = 0; j < 8; ++j) { S += rs[j]; SS += rss[j]; }
    const float inv = 1.0f / (float)(B_ * HID_);
    float mean = S * inv;
    float var  = SS * inv - mean * mean;       // biased, matches jnp.var
    float sc = g1[g] * rsqrtf(var + EPS_);
    float sh = be1[g] - mean * sc;

    // ---- normalize + ReLU -> LA (bf16) ----
#pragma unroll
    for (int mt = 0; mt < 2; ++mt)
#pragma unroll
        for (int nt = 0; nt < 2; ++nt)
#pragma unroll
            for (int r = 0; r < 4; ++r) {
                float y = fmaxf(fmaf(acc[mt][nt][r], sc, sh), 0.f);
                __hip_bfloat16 hb = __float2bfloat16(y);
                LA[(mt * 16 + kg * 4 + r) * LAP_ + (w * 32 + nt * 16 + lm)] =
                    *reinterpret_cast<unsigned short*>(&hb);
            }
    __syncthreads();

    // ---- GEMM2 via MFMA ----
    f32x4 a2[2][2];
#pragma unroll
    for (int mt = 0; mt < 2; ++mt)
#pragma unroll
        for (int nt = 0; nt < 2; ++nt)
#pragma unroll
            for (int r = 0; r < 4; ++r) a2[mt][nt][r] = 0.f;

#pragma unroll
    for (int ks = 0; ks < 8; ++ks) {
        short8_t af[2], bfm[2];
#pragma unroll
        for (int mt = 0; mt < 2; ++mt)
            af[mt] = *(const short8_t*)&LA[(mt * 16 + lm) * LAP_ + ks * 32 + kg8];
#pragma unroll
        for (int nt = 0; nt < 2; ++nt)
            bfm[nt] = *(const short8_t*)&w2bf[(size_t)(w * 32 + nt * 16 + lm) * 256 +
                                              ks * 32 + kg8];
#pragma unroll
        for (int mt = 0; mt < 2; ++mt)
#pragma unroll
            for (int nt = 0; nt < 2; ++nt)
                a2[mt][nt] = __builtin_amdgcn_mfma_f32_16x16x32_bf16(
                    af[mt], bfm[nt], a2[mt][nt], 0, 0, 0);
    }

    // ---- + b2, BN2 stats ----
    float b2v0 = b2[w * 32 + lm], b2v1 = b2[w * 32 + 16 + lm];
    float s2 = 0.f, ss2 = 0.f;
#pragma unroll
    for (int mt = 0; mt < 2; ++mt)
#pragma unroll
        for (int nt = 0; nt < 2; ++nt)
#pragma unroll
            for (int r = 0; r < 4; ++r) {
                float v = a2[mt][nt][r] + (nt ? b2v1 : b2v0);
                a2[mt][nt][r] = v;
                s2 += v; ss2 += v * v;
            }
#pragma unroll
    for (int o = 32; o > 0; o >>= 1) { s2 += __shfl_down(s2, o); ss2 += __shfl_down(ss2, o); }
    if (l == 0) { rs[w] = s2; rss[w] = ss2; }   // safe: BN1 rs reads pre-barrier
    __syncthreads();
    float S2 = 0.f, SS2 = 0.f;
#pragma unroll
    for (int j = 0; j < 8; ++j) { S2 += rs[j]; SS2 += rss[j]; }
    float mean2 = S2 * inv;
    float var2  = SS2 * inv - mean2 * mean2;
    float sc2 = g2[g] * rsqrtf(var2 + EPS_);
    float sh2 = be2[g] - mean2 * sc2;

#pragma unroll
    for (int mt = 0; mt < 2; ++mt)
#pragma unroll
        for (int nt = 0; nt < 2; ++nt)
#pragma unroll
            for (int r = 0; r < 4; ++r) {
                int b = mt * 16 + kg * 4 + r;
                int z = w * 32 + nt * 16 + lm;
                zout[((size_t)b * G_ + g) * 256 + z] =
                    fmaxf(fmaf(a2[mt][nt][r], sc2, sh2), 0.f);
            }
}

// ---------------------------------------------------------------------------
extern "C" void kernel_launch(void* const* d_in, const int* in_sizes, int n_in,
                              void* d_out, int out_size, void* d_ws, size_t ws_size,
                              hipStream_t stream) {
    const float* x    = (const float*)d_in[0];
    const float* mask = (const float*)d_in[1];
    const float* W1   = (const float*)d_in[2];
    const float* b1   = (const float*)d_in[3];
    const float* g1   = (const float*)d_in[4];
    const float* be1  = (const float*)d_in[5];
    const float* W2   = (const float*)d_in[6];
    const float* b2   = (const float*)d_in[7];
    const float* g2   = (const float*)d_in[8];
    const float* be2  = (const float*)d_in[9];
    float* out = (float*)d_out;

    char* ws = (char*)d_ws;
    size_t off = 0;
    auto take = [&](size_t bytes) {
        char* p = ws + off;
        off = (off + bytes + 255) & ~(size_t)255;
        return p;
    };
    __hip_bfloat16* w1bf = (__hip_bfloat16*)take((size_t)(N_ + 1) * HID_ * 2); // (N+1,HID)
    __hip_bfloat16* xtbf = (__hip_bfloat16*)take((size_t)(N_ + 1) * B_ * 2);   // (N+1,B)
    __hip_bfloat16* w2bf = (__hip_bfloat16*)take((size_t)HID_ * HID_ * 2);     // (Z,HID)
    float* h             = (float*)take((size_t)G_ * B_ * HID_ * 4);           // 8MB
    float* hpartD        = (float*)take((size_t)DKB_ * B_ * HID_ * 4);
    int* cnt             = (int*)take((size_t)G_ * 4);
    unsigned short* idx  = (unsigned short*)take((size_t)G_ * N_ * 2);

    prep_k<<<PREP_GRID, 256, 0, stream>>>(W1, x, W2, mask, w1bf, xtbf, w2bf,
                                          cnt, idx);
    gemm1_k<<<G1_GRID, 512, 0, stream>>>((const unsigned short*)w1bf,
                                         (const unsigned short*)xtbf,
                                         cnt, idx, b1, h, hpartD);
    reduce_k<<<(B_ * HID_) / 256, 256, 0, stream>>>(hpartD, b1, h);
    fused_k<<<G_, 512, 0, stream>>>(h, g1, be1,
                                    (const unsigned short*)w2bf,
                                    b2, g2, be2, out);
}

// Round 20
// 43.980 us; speedup vs baseline: 2.2399x; 1.2172x over previous
//
#include <hip/hip_runtime.h>
#include <hip/hip_bf16.h>

#define B_    32
#define N_    10000
#define G_    256
#define HID_  256
#define EPS_  1e-5f

typedef __attribute__((ext_vector_type(8))) short short8_t;
typedef __attribute__((ext_vector_type(4))) float f32x4;

// prep_k grid segmentation
#define TB_W1  2504            // W1 transpose->bf16: 313 x 8 tiles
#define TB_X   313             // x transpose->bf16: 32 x 10000
#define NB_W2C 64              // W2 -> bf16 cast (no transpose)
#define NB_CMP 256             // mask compaction, one block per g
#define PREP_GRID (TB_W1 + TB_X + NB_W2C + NB_CMP + 1)   // 3138 (+1 zero-row)

#define DKB_  64               // dense-group split-K producer blocks (mult of 8)
#define DCH_  157              // genes per dense chunk (64*157 >= 10000)
#define G1_GRID (DKB_ + 255)   // 319: producers first (balanced ~5 tiles each),
                               // sparse g at bid 64+g == g (mod 8) -> same XCD
                               // as fused_k's block g => h[g] L2-local.

#define LAP_  264              // LA pitch in elements (16B-aligned rows)

// ---------------------------------------------------------------------------
// Tiled transpose helper (f32 -> bf16).
// ---------------------------------------------------------------------------
__device__ inline void transpose_tile_bf16(const float* __restrict__ src,
                                           __hip_bfloat16* __restrict__ dst,
                                           int R, int C, int bx, int by, int t,
                                           float (*tile)[33]) {
    int tx = t & 31, ty = t >> 5;      // 32 x 8
    int c0 = bx * 32, r0 = by * 32;
#pragma unroll
    for (int j = 0; j < 4; ++j) {
        int r = r0 + ty + j * 8, c = c0 + tx;
        if (r < R && c < C) tile[ty + j * 8][tx] = src[(size_t)r * C + c];
    }
    __syncthreads();
#pragma unroll
    for (int j = 0; j < 4; ++j) {
        int c = c0 + ty + j * 8, r = r0 + tx;
        if (r < R && c < C)
            dst[(size_t)c * R + r] = __float2bfloat16(tile[tx][ty + j * 8]);
    }
}

// ---------------------------------------------------------------------------
// Fused prep: W1/x -> bf16 transposes, W2 -> bf16 cast, compaction (float4
// mask reads), zero-row.
// ---------------------------------------------------------------------------
__global__ __launch_bounds__(256) void prep_k(const float* __restrict__ W1,
                                              const float* __restrict__ x,
                                              const float* __restrict__ W2,
                                              const float* __restrict__ mask,
                                              __hip_bfloat16* __restrict__ w1bf,
                                              __hip_bfloat16* __restrict__ xtbf,
                                              __hip_bfloat16* __restrict__ w2bf,
                                              int* __restrict__ cnt,
                                              unsigned short* __restrict__ idx) {
    __shared__ float tile[32][33];
    __shared__ int c;
    int bid = blockIdx.x, t = threadIdx.x;

    if (bid < TB_W1) {
        transpose_tile_bf16(W1, w1bf, HID_, N_, bid % 313, bid / 313, t, tile);
    } else if (bid < TB_W1 + TB_X) {
        transpose_tile_bf16(x, xtbf, B_, N_, bid - TB_W1, 0, t, tile);
    } else if (bid < TB_W1 + TB_X + NB_W2C) {
        int b = bid - (TB_W1 + TB_X);
#pragma unroll
        for (int j = 0; j < 4; ++j) {
            int i = b * 1024 + j * 256 + t;
            w2bf[i] = __float2bfloat16(W2[i]);
        }
    } else if (bid < TB_W1 + TB_X + NB_W2C + NB_CMP) {
        int g = bid - (TB_W1 + TB_X + NB_W2C);
        if (g == 255) return;              // dense group: contiguous, no list
        if (t == 0) c = 0;
        __syncthreads();
        const float4* m4 = (const float4*)(mask + (size_t)g * N_);
        for (int i = t; i < N_ / 4; i += 256) {      // vectorized mask read
            float4 mv = m4[i];
            if (mv.x != 0.0f) idx[(size_t)g * N_ + atomicAdd(&c, 1)] = (unsigned short)(4 * i + 0);
            if (mv.y != 0.0f) idx[(size_t)g * N_ + atomicAdd(&c, 1)] = (unsigned short)(4 * i + 1);
            if (mv.z != 0.0f) idx[(size_t)g * N_ + atomicAdd(&c, 1)] = (unsigned short)(4 * i + 2);
            if (mv.w != 0.0f) idx[(size_t)g * N_ + atomicAdd(&c, 1)] = (unsigned short)(4 * i + 3);
        }
        __syncthreads();
        if (t == 0) cnt[g] = c;
    } else {
        // zero row N_ of w1bf and xtbf (pad-gene target: contributes 0)
        w1bf[(size_t)N_ * 256 + t] = __float2bfloat16(0.f);
        if (t < 32) xtbf[(size_t)N_ * 32 + t] = __float2bfloat16(0.f);
    }
}

// ---------------------------------------------------------------------------
// GEMM1 via MFMA, direct-global fragment gather. ZERO LDS, no sync objects.
//   bid <  64  : dense producer (group 255, ~157 genes) -> hpartD[bid]
//   bid 64..318: sparse group g = bid-64 -> h[g] (+b1), straight from regs
// All blocks ~5-7 MFMA tiles -> balanced grid, no straggler tail.
// 512 threads = 8 waves. Wave w owns output cols [w*32, w*32+32).
// Fragments (HW-verified round 11):
//   A: lane l -> A[l&15][(l>>4)*8+j]       (A[b][k] = x_bf16[gene_k][b])
//   B: lane l -> B[(l>>4)*8+j][l&15]       (B[k][h] = W1_bf16[gene_k][h])
//   C/D: lane l reg r -> D[(l>>4)*4+r][l&15]  => global write row*256+col
// Tail genes -> zero-row N_ (branchless).
// ---------------------------------------------------------------------------
__global__ __launch_bounds__(512, 2) void gemm1_k(const unsigned short* __restrict__ w1bf,
                                                  const unsigned short* __restrict__ xtbf,
                                                  const int* __restrict__ cnt,
                                                  const unsigned short* __restrict__ idx,
                                                  const float* __restrict__ b1,
                                                  float* __restrict__ h,
                                                  float* __restrict__ hpartD) {
    const int t = threadIdx.x, bid = blockIdx.x;
    const int w   = t >> 6;
    const int l   = t & 63;
    const int lm  = l & 15;
    const int kg  = l >> 4;
    const int kg8 = kg * 8;

    const bool producer = (bid < DKB_);
    const int g = producer ? 255 : (bid - DKB_);

    f32x4 acc[2][2];
#pragma unroll
    for (int mt = 0; mt < 2; ++mt)
#pragma unroll
        for (int nt = 0; nt < 2; ++nt)
#pragma unroll
            for (int r = 0; r < 4; ++r) acc[mt][nt][r] = 0.f;

    const int k0   = producer ? bid * DCH_ : 0;
    const int kend = producer ? max(0, min(N_ - k0, DCH_)) : cnt[g];
    const unsigned short* lp = idx + (size_t)g * N_;

    for (int base = 0; base < kend; base += 32) {
        int nj[8];
        if (!producer) {
            uint4 ip = *(const uint4*)(lp + base + kg8);   // 16B, aligned
            unsigned int uu[4] = {ip.x, ip.y, ip.z, ip.w};
#pragma unroll
            for (int j = 0; j < 8; ++j) {
                int kk = base + kg8 + j;
                int nv = (int)((uu[j >> 1] >> ((j & 1) * 16)) & 0xffffu);
                nj[j] = (kk < kend) ? nv : N_;             // pad -> zero row
            }
        } else {
#pragma unroll
            for (int j = 0; j < 8; ++j) {
                int kk = base + kg8 + j;
                nj[j] = (kk < kend) ? (k0 + kk) : N_;
            }
        }
        short8_t af0, af1, bf0, bf1;
#pragma unroll
        for (int j = 0; j < 8; ++j) {
            const int n = nj[j];
            af0[j] = (short)xtbf[(size_t)n * 32 + lm];             // A[b][k]
            af1[j] = (short)xtbf[(size_t)n * 32 + 16 + lm];
            bf0[j] = (short)w1bf[(size_t)n * 256 + w * 32 + lm];   // B[k][h]
            bf1[j] = (short)w1bf[(size_t)n * 256 + w * 32 + 16 + lm];
        }
        acc[0][0] = __builtin_amdgcn_mfma_f32_16x16x32_bf16(af0, bf0, acc[0][0], 0, 0, 0);
        acc[0][1] = __builtin_amdgcn_mfma_f32_16x16x32_bf16(af0, bf1, acc[0][1], 0, 0, 0);
        acc[1][0] = __builtin_amdgcn_mfma_f32_16x16x32_bf16(af1, bf0, acc[1][0], 0, 0, 0);
        acc[1][1] = __builtin_amdgcn_mfma_f32_16x16x32_bf16(af1, bf1, acc[1][1], 0, 0, 0);
    }

    if (producer) {
        float* dst = hpartD + (size_t)bid * 8192;
#pragma unroll
        for (int mt = 0; mt < 2; ++mt)
#pragma unroll
            for (int nt = 0; nt < 2; ++nt)
#pragma unroll
                for (int r = 0; r < 4; ++r)
                    dst[(mt * 16 + kg * 4 + r) * 256 + (w * 32 + nt * 16 + lm)] =
                        acc[mt][nt][r];
    } else {
        float b1v0 = b1[w * 32 + lm], b1v1 = b1[w * 32 + 16 + lm];
        float* dst = h + (size_t)g * 8192;
#pragma unroll
        for (int mt = 0; mt < 2; ++mt)
#pragma unroll
            for (int nt = 0; nt < 2; ++nt)
#pragma unroll
                for (int r = 0; r < 4; ++r)
                    dst[(mt * 16 + kg * 4 + r) * 256 + (w * 32 + nt * 16 + lm)] =
                        acc[mt][nt][r] + (nt ? b1v1 : b1v0);
    }
}

// ---------------------------------------------------------------------------
// Dense-group reduction: h[255][i] = b1 + sum over 64 chunks (MLP-friendly).
// ---------------------------------------------------------------------------
__global__ __launch_bounds__(256) void reduce_k(const float* __restrict__ hpartD,
                                                const float* __restrict__ b1,
                                                float* __restrict__ h) {
    int i = blockIdx.x * 256 + threadIdx.x;   // 0..8191
    float p0 = 0.f, p1 = 0.f, p2 = 0.f, p3 = 0.f;
#pragma unroll 4
    for (int kb = 0; kb < DKB_; kb += 4) {
        p0 += hpartD[(size_t)(kb + 0) * 8192 + i];
        p1 += hpartD[(size_t)(kb + 1) * 8192 + i];
        p2 += hpartD[(size_t)(kb + 2) * 8192 + i];
        p3 += hpartD[(size_t)(kb + 3) * 8192 + i];
    }
    h[(size_t)255 * 8192 + i] = b1[i & 255] + ((p0 + p1) + (p2 + p3));
}

// ---------------------------------------------------------------------------
// Fused tail: h[g] -> BN1+ReLU -> GEMM2 (MFMA) -> BN2+ReLU -> out.
// One block per group, 512 threads. h loads go straight into the C/D
// register layout (4 x 64B segments per load inst). LDS = LA only (17KB).
// ---------------------------------------------------------------------------
__global__ __launch_bounds__(512, 2) void fused_k(const float* __restrict__ h,
                                                  const float* __restrict__ g1,
                                                  const float* __restrict__ be1,
                                                  const unsigned short* __restrict__ w2bf,
                                                  const float* __restrict__ b2,
                                                  const float* __restrict__ g2,
                                                  const float* __restrict__ be2,
                                                  float* __restrict__ zout) {
    __shared__ unsigned short LA[32 * LAP_];   // 16.9 KB
    __shared__ float rs[8], rss[8];

    const int t = threadIdx.x, g = blockIdx.x;
    const int w   = t >> 6;
    const int l   = t & 63;
    const int lm  = l & 15;
    const int kg  = l >> 4;
    const int kg8 = kg * 8;

    // ---- load h[g] into C/D-layout registers, accumulate BN1 stats ----
    const float* hg = h + (size_t)g * 8192;
    f32x4 acc[2][2];
    float s = 0.f, ss = 0.f;
#pragma unroll
    for (int mt = 0; mt < 2; ++mt)
#pragma unroll
        for (int nt = 0; nt < 2; ++nt)
#pragma unroll
            for (int r = 0; r < 4; ++r) {
                float v = hg[(mt * 16 + kg * 4 + r) * 256 + (w * 32 + nt * 16 + lm)];
                acc[mt][nt][r] = v;
                s += v; ss += v * v;
            }
#pragma unroll
    for (int o = 32; o > 0; o >>= 1) { s += __shfl_down(s, o); ss += __shfl_down(ss, o); }
    if (l == 0) { rs[w] = s; rss[w] = ss; }
    __syncthreads();
    float S = 0.f, SS = 0.f;
#pragma unroll
    for (int j = 0; j < 8; ++j) { S += rs[j]; SS += rss[j]; }
    const float inv = 1.0f / (float)(B_ * HID_);
    float mean = S * inv;
    float var  = SS * inv - mean * mean;       // biased, matches jnp.var
    float sc = g1[g] * rsqrtf(var + EPS_);
    float sh = be1[g] - mean * sc;

    // ---- normalize + ReLU -> LA (bf16) ----
#pragma unroll
    for (int mt = 0; mt < 2; ++mt)
#pragma unroll
        for (int nt = 0; nt < 2; ++nt)
#pragma unroll
            for (int r = 0; r < 4; ++r) {
                float y = fmaxf(fmaf(acc[mt][nt][r], sc, sh), 0.f);
                __hip_bfloat16 hb = __float2bfloat16(y);
                LA[(mt * 16 + kg * 4 + r) * LAP_ + (w * 32 + nt * 16 + lm)] =
                    *reinterpret_cast<unsigned short*>(&hb);
            }
    __syncthreads();

    // ---- GEMM2 via MFMA ----
    f32x4 a2[2][2];
#pragma unroll
    for (int mt = 0; mt < 2; ++mt)
#pragma unroll
        for (int nt = 0; nt < 2; ++nt)
#pragma unroll
            for (int r = 0; r < 4; ++r) a2[mt][nt][r] = 0.f;

#pragma unroll
    for (int ks = 0; ks < 8; ++ks) {
        short8_t af[2], bfm[2];
#pragma unroll
        for (int mt = 0; mt < 2; ++mt)
            af[mt] = *(const short8_t*)&LA[(mt * 16 + lm) * LAP_ + ks * 32 + kg8];
#pragma unroll
        for (int nt = 0; nt < 2; ++nt)
            bfm[nt] = *(const short8_t*)&w2bf[(size_t)(w * 32 + nt * 16 + lm) * 256 +
                                              ks * 32 + kg8];
#pragma unroll
        for (int mt = 0; mt < 2; ++mt)
#pragma unroll
            for (int nt = 0; nt < 2; ++nt)
                a2[mt][nt] = __builtin_amdgcn_mfma_f32_16x16x32_bf16(
                    af[mt], bfm[nt], a2[mt][nt], 0, 0, 0);
    }

    // ---- + b2, BN2 stats ----
    float b2v0 = b2[w * 32 + lm], b2v1 = b2[w * 32 + 16 + lm];
    float s2 = 0.f, ss2 = 0.f;
#pragma unroll
    for (int mt = 0; mt < 2; ++mt)
#pragma unroll
        for (int nt = 0; nt < 2; ++nt)
#pragma unroll
            for (int r = 0; r < 4; ++r) {
                float v = a2[mt][nt][r] + (nt ? b2v1 : b2v0);
                a2[mt][nt][r] = v;
                s2 += v; ss2 += v * v;
            }
#pragma unroll
    for (int o = 32; o > 0; o >>= 1) { s2 += __shfl_down(s2, o); ss2 += __shfl_down(ss2, o); }
    if (l == 0) { rs[w] = s2; rss[w] = ss2; }   // safe: BN1 rs reads pre-barrier
    __syncthreads();
    float S2 = 0.f, SS2 = 0.f;
#pragma unroll
    for (int j = 0; j < 8; ++j) { S2 += rs[j]; SS2 += rss[j]; }
    float mean2 = S2 * inv;
    float var2  = SS2 * inv - mean2 * mean2;
    float sc2 = g2[g] * rsqrtf(var2 + EPS_);
    float sh2 = be2[g] - mean2 * sc2;

#pragma unroll
    for (int mt = 0; mt < 2; ++mt)
#pragma unroll
        for (int nt = 0; nt < 2; ++nt)
#pragma unroll
            for (int r = 0; r < 4; ++r) {
                int b = mt * 16 + kg * 4 + r;
                int z = w * 32 + nt * 16 + lm;
                zout[((size_t)b * G_ + g) * 256 + z] =
                    fmaxf(fmaf(a2[mt][nt][r], sc2, sh2), 0.f);
            }
}

// ---------------------------------------------------------------------------
extern "C" void kernel_launch(void* const* d_in, const int* in_sizes, int n_in,
                              void* d_out, int out_size, void* d_ws, size_t ws_size,
                              hipStream_t stream) {
    const float* x    = (const float*)d_in[0];
    const float* mask = (const float*)d_in[1];
    const float* W1   = (const float*)d_in[2];
    const float* b1   = (const float*)d_in[3];
    const float* g1   = (const float*)d_in[4];
    const float* be1  = (const float*)d_in[5];
    const float* W2   = (const float*)d_in[6];
    const float* b2   = (const float*)d_in[7];
    const float* g2   = (const float*)d_in[8];
    const float* be2  = (const float*)d_in[9];
    float* out = (float*)d_out;

    char* ws = (char*)d_ws;
    size_t off = 0;
    auto take = [&](size_t bytes) {
        char* p = ws + off;
        off = (off + bytes + 255) & ~(size_t)255;
        return p;
    };
    __hip_bfloat16* w1bf = (__hip_bfloat16*)take((size_t)(N_ + 1) * HID_ * 2); // (N+1,HID)
    __hip_bfloat16* xtbf = (__hip_bfloat16*)take((size_t)(N_ + 1) * B_ * 2);   // (N+1,B)
    __hip_bfloat16* w2bf = (__hip_bfloat16*)take((size_t)HID_ * HID_ * 2);     // (Z,HID)
    float* h             = (float*)take((size_t)G_ * B_ * HID_ * 4);           // 8MB
    float* hpartD        = (float*)take((size_t)DKB_ * B_ * HID_ * 4);         // 2MB
    int* cnt             = (int*)take((size_t)G_ * 4);
    unsigned short* idx  = (unsigned short*)take((size_t)G_ * N_ * 2);

    prep_k<<<PREP_GRID, 256, 0, stream>>>(W1, x, W2, mask, w1bf, xtbf, w2bf,
                                          cnt, idx);
    gemm1_k<<<G1_GRID, 512, 0, stream>>>((const unsigned short*)w1bf,
                                         (const unsigned short*)xtbf,
                                         cnt, idx, b1, h, hpartD);
    reduce_k<<<(B_ * HID_) / 256, 256, 0, stream>>>(hpartD, b1, h);
    fused_k<<<G_, 512, 0, stream>>>(h, g1, be1,
                                    (const unsigned short*)w2bf,
                                    b2, g2, be2, out);
}